// Round 12
// baseline (293.456 us; speedup 1.0000x reference)
//
#include <hip/hip_runtime.h>
#include <hip/hip_bf16.h>
#include <math.h>

#define D 128
typedef unsigned int uint;
typedef unsigned short ushort;

using bf16x8 = __attribute__((ext_vector_type(8))) short;
using f32x4  = __attribute__((ext_vector_type(4))) float;
using f32x2  = __attribute__((ext_vector_type(2))) float;

static __device__ __forceinline__ ushort f2b(float f) {
    __hip_bfloat16 h = __float2bfloat16(f);
    return __builtin_bit_cast(ushort, h);
}
static __device__ __forceinline__ float blo(uint u) {
    uint v = u << 16;
    return __builtin_bit_cast(float, v);
}
static __device__ __forceinline__ float bhi(uint u) {
    uint v = u & 0xFFFF0000u;
    return __builtin_bit_cast(float, v);
}

#define NBLK_A 1024     // blocks for coarse count/place passes
#define MAXB   128      // max coarse buckets (nN <= 128K)
#define WTOT   (2*128*256 + 80*128)

// ---------------------------------------------------------------- pass A
// Coarse LDS histogram (bucket = dst>>10) per block chunk + fused cast/weights.
__global__ __launch_bounds__(256) void k_bcount(
    const int* __restrict__ dst, int* __restrict__ cnt, int E, int nbuck,
    const float* __restrict__ x, ushort* __restrict__ Abuf, int n4,
    const float* __restrict__ Wl0, const float* __restrict__ Wr0,
    const float* __restrict__ Wl1, const float* __restrict__ Wr1,
    const float* __restrict__ Wl2, const float* __restrict__ Wr2,
    ushort* __restrict__ Wtg0, ushort* __restrict__ Wtg1,
    ushort* __restrict__ W2tg)
{
    __shared__ int h[MAXB];
    int tid = threadIdx.x, b = blockIdx.x;
    for (int k = tid; k < nbuck; k += 256) h[k] = 0;
    __syncthreads();
    int chunk = (E + NBLK_A - 1) / NBLK_A;
    int beg = b * chunk, end = min(beg + chunk, E);
    for (int e = beg + tid; e < end; e += 256)
        atomicAdd(&h[dst[e] >> 10], 1);
    __syncthreads();
    for (int k = tid; k < nbuck; k += 256) cnt[k * NBLK_A + b] = h[k];

    // fused bf16 cast of x into AbufA cols 128..255
    for (int i = b * 256 + tid; i < n4; i += NBLK_A * 256) {
        float4 v = *(const float4*)(x + (size_t)i * 4);
        int node = i >> 5, coff = (i & 31) * 4;
        ushort4 o;
        o.x = f2b(v.x); o.y = f2b(v.y); o.z = f2b(v.z); o.w = f2b(v.w);
        *(ushort4*)(Abuf + (size_t)node * 256 + 128 + coff) = o;
    }
    // fused weight prep
    for (int i = b * 256 + tid; i < WTOT; i += NBLK_A * 256) {
        if (i < 2 * 128 * 256) {
            int which = i >> 15;
            int o = i & 32767;
            int j = o >> 8, kk = o & 255;
            const float* Wl = which ? Wl1 : Wl0;
            const float* Wr = which ? Wr1 : Wr0;
            float v = (kk < 128) ? Wl[j * 128 + kk] : Wr[j * 128 + (kk - 128)];
            (which ? Wtg1 : Wtg0)[o] = f2b(v);
        } else {
            int o = i - 2 * 128 * 256;
            int j = o >> 7, kk = o & 127;
            float v = (j < 40) ? Wl2[j * 128 + kk] : Wr2[(j - 40) * 128 + kk];
            W2tg[o] = f2b(v);
        }
    }
}

// ---------------------------------------------------------------- hierarchical scan
__global__ __launch_bounds__(256) void k_scanA(int* __restrict__ a,
                                               int* __restrict__ bsum, int n) {
    __shared__ int s[256];
    int tid = threadIdx.x;
    int i = blockIdx.x * 256 + tid;
    int v = (i < n) ? a[i] : 0;
    s[tid] = v;
    __syncthreads();
#pragma unroll
    for (int o = 1; o < 256; o <<= 1) {
        int t = (tid >= o) ? s[tid - o] : 0;
        __syncthreads();
        s[tid] += t;
        __syncthreads();
    }
    if (i < n) a[i] = s[tid] - v;
    if (tid == 255) bsum[blockIdx.x] = s[255];
}

// scan of block sums + bucket-base extraction.
__global__ void k_scan2(int* __restrict__ bsum, int nb,
                        int* __restrict__ bb, int nbuck, int E) {
    __shared__ int s[512];
    __shared__ int carry_s;
    int tid = threadIdx.x;
    if (tid == 0) carry_s = 0;
    __syncthreads();
    for (int base = 0; base < nb; base += 512) {
        int i = base + tid;
        int v = (i < nb) ? bsum[i] : 0;
        s[tid] = v;
        __syncthreads();
#pragma unroll
        for (int o = 1; o < 512; o <<= 1) {
            int t = (tid >= o) ? s[tid - o] : 0;
            __syncthreads();
            s[tid] += t;
            __syncthreads();
        }
        int carry = carry_s;
        if (i < nb) bsum[i] = s[tid] - v + carry;
        int total = s[511];
        __syncthreads();
        if (tid == 0) carry_s = carry + total;
        __syncthreads();
    }
    for (int k = tid; k < nbuck; k += 512) bb[k] = bsum[k * (NBLK_A >> 8)];
    if (tid == 0) bb[nbuck] = E;
}

// ---------------------------------------------------------------- pass C
// ebuf packed: src in bits 0..19, fine bin (dst&1023) in bits 20..29.
__global__ __launch_bounds__(256) void k_bplace(
    const int* __restrict__ src, const int* __restrict__ dst,
    const int* __restrict__ cnt, const int* __restrict__ bsum,
    uint* __restrict__ ebuf, int E, int nbuck)
{
    __shared__ int cur[MAXB];
    int tid = threadIdx.x, b = blockIdx.x;
    for (int k = tid; k < nbuck; k += 256) {
        int idx = k * NBLK_A + b;
        cur[k] = cnt[idx] + bsum[idx >> 8];
    }
    __syncthreads();
    int chunk = (E + NBLK_A - 1) / NBLK_A;
    int beg = b * chunk, end = min(beg + chunk, E);
    for (int e = beg + tid; e < end; e += 256) {
        int d = dst[e];
        int r = atomicAdd(&cur[d >> 10], 1);
        ebuf[r] = (uint)src[e] | ((uint)(d & 1023) << 20);
    }
}

// ---------------------------------------------------------------- pass D
__global__ __launch_bounds__(1024) void k_bfine(
    const uint* __restrict__ ebuf, const int* __restrict__ bb,
    int* __restrict__ rowptr, int* __restrict__ col, int nN, int nbuck, int E)
{
    __shared__ int cnt2[1024];
    __shared__ int sc[1024];
    int k = blockIdx.x, tid = threadIdx.x;
    int e0 = bb[k], e1 = bb[k + 1];
    cnt2[tid] = 0;
    __syncthreads();
    for (int e = e0 + tid; e < e1; e += 1024)
        atomicAdd(&cnt2[ebuf[e] >> 20], 1);
    __syncthreads();
    int v = cnt2[tid];
    sc[tid] = v;
    __syncthreads();
#pragma unroll
    for (int o = 1; o < 1024; o <<= 1) {
        int t = (tid >= o) ? sc[tid - o] : 0;
        __syncthreads();
        sc[tid] += t;
        __syncthreads();
    }
    int excl = sc[tid] - v;
    int node = k * 1024 + tid;
    if (node < nN) rowptr[node] = e0 + excl;
    if (k == nbuck - 1 && tid == 0) rowptr[nN] = E;
    cnt2[tid] = e0 + excl;       // reuse as cursor
    __syncthreads();
    for (int e = e0 + tid; e < e1; e += 1024) {
        uint sd = ebuf[e];
        int r = atomicAdd(&cnt2[sd >> 20], 1);
        col[r] = (int)(sd & 0xFFFFFu);
    }
}

// ---------------------------------------------------------------- 128-dim mean-gather
// 2 nodes per wave: h=lane>>5 picks node, 2 edge slots x 16 chunks of 16B.
__global__ __launch_bounds__(256) void k_gather128(
    const ushort* __restrict__ feat, ushort* __restrict__ agg,
    const int* __restrict__ rowptr, const int* __restrict__ col, int nN)
{
    int tid = threadIdx.x;
    int lane = tid & 63;
    int h = lane >> 5;
    int node = blockIdx.x * 8 + ((tid >> 6) << 1) + h;
    if (node >= nN) return;
    int g = (lane >> 4) & 1;    // edge slot 0..1
    int r = lane & 15;          // 16B chunk -> cols 8r..8r+7
    int beg = rowptr[node], end = rowptr[node + 1];
    const char* fb = (const char*)feat;
    const uint rb = (uint)(r << 4);
    float a[8];
#pragma unroll
    for (int i = 0; i < 8; ++i) a[i] = 0.f;

    int j = beg + g;
    for (; j + 2 < end; j += 4) {          // 4 edges/node per unrolled iter
        int s0 = col[j], s1 = col[j + 2];
        uint4 v0 = *(const uint4*)(fb + (((uint)s0 << 9) + rb));
        uint4 v1 = *(const uint4*)(fb + (((uint)s1 << 9) + rb));
        const uint* p0 = (const uint*)&v0;
        const uint* p1 = (const uint*)&v1;
#pragma unroll
        for (int i = 0; i < 4; ++i) {
            a[2 * i]     += blo(p0[i]) + blo(p1[i]);
            a[2 * i + 1] += bhi(p0[i]) + bhi(p1[i]);
        }
    }
    if (j < end) {
        int s0 = col[j];
        uint4 v0 = *(const uint4*)(fb + (((uint)s0 << 9) + rb));
        const uint* p0 = (const uint*)&v0;
#pragma unroll
        for (int i = 0; i < 4; ++i) {
            a[2 * i]     += blo(p0[i]);
            a[2 * i + 1] += bhi(p0[i]);
        }
    }
#pragma unroll
    for (int i = 0; i < 8; ++i)
        a[i] += __shfl_xor(a[i], 16);      // reduce across the 2 slots
    if (g == 0) {
        float inv = 1.0f / (float)max(end - beg, 1);
        uint4 o;
        uint* po = (uint*)&o;
#pragma unroll
        for (int i = 0; i < 4; ++i)
            po[i] = (uint)f2b(a[2 * i] * inv) | ((uint)f2b(a[2 * i + 1] * inv) << 16);
        *(uint4*)(agg + (size_t)node * 256 + r * 8) = o;
    }
}

// ---------------------------------------------------------------- MFMA GEMM (layer 0)
// Full-K weight tile (66 KB LDS, 2 blocks/CU); A latency hidden by ILP:
// all 16 A-loads (2 rows x 8 ksteps) issue upfront and complete under the
// weight-staging + barrier shadow (occupancy is LDS-bound, VGPRs are free).
__global__ __launch_bounds__(256) void k_gemm_mfma(
    const ushort* __restrict__ A, int astride,
    const ushort* __restrict__ Wt, const float* __restrict__ bias,
    ushort* __restrict__ out, int ostride, int nN)
{
    constexpr int SW = 264;
    __shared__ __align__(16) ushort Ws[128 * SW];

    const int tid = threadIdx.x;
    const int l = tid & 63, wv = tid >> 6;
    const int q = l >> 4, r = l & 15;
    const long long m0 = (long long)blockIdx.x * 128 + wv * 32;
    const int mA = (int)min(m0 + r, (long long)(nN - 1));
    const int mB = (int)min(m0 + 16 + r, (long long)(nN - 1));
    const ushort* pa = A + (size_t)mA * astride + q * 8;
    const ushort* pb = A + (size_t)mB * astride + q * 8;

    // issue ALL A-loads first: 16 independent dwordx4 in flight
    bf16x8 aR0[8], aR1[8];
#pragma unroll
    for (int ks = 0; ks < 8; ++ks) {
        aR0[ks] = *(const bf16x8*)(pa + ks * 32);
        aR1[ks] = *(const bf16x8*)(pb + ks * 32);
    }

#pragma unroll
    for (int c = tid; c < 128 * 32; c += 256) {
        int row = c >> 5;
        int ko  = (c & 31) * 8;
        *(uint4*)(Ws + row * SW + ko) = *(const uint4*)(Wt + row * 256 + ko);
    }
    __syncthreads();

    f32x4 acc[2][8];
#pragma unroll
    for (int mt = 0; mt < 2; ++mt)
#pragma unroll
        for (int nt = 0; nt < 8; ++nt)
            acc[mt][nt] = (f32x4){0.f, 0.f, 0.f, 0.f};

#pragma unroll
    for (int ks = 0; ks < 8; ++ks) {
#pragma unroll
        for (int nt = 0; nt < 8; ++nt) {
            bf16x8 b = *(const bf16x8*)(Ws + (nt * 16 + r) * SW + ks * 32 + q * 8);
            acc[0][nt] = __builtin_amdgcn_mfma_f32_16x16x32_bf16(aR0[ks], b, acc[0][nt], 0, 0, 0);
            acc[1][nt] = __builtin_amdgcn_mfma_f32_16x16x32_bf16(aR1[ks], b, acc[1][nt], 0, 0, 0);
        }
    }

#pragma unroll
    for (int mt = 0; mt < 2; ++mt) {
#pragma unroll
        for (int i = 0; i < 4; ++i) {
            long long m = m0 + mt * 16 + q * 4 + i;
            if (m >= nN) continue;
#pragma unroll
            for (int nt = 0; nt < 8; ++nt) {
                int cc = nt * 16 + r;
                float v = acc[mt][nt][i] + bias[cc];
                v = fmaxf(v, 0.f);
                out[(size_t)m * ostride + cc] = f2b(v);
            }
        }
    }
}

// ---------------------------------------------------------------- fused layer-1 GEMM + layer-2 projection
// Phase A: h2 = relu(A.Wt1 + b1) kept in LDS only (h2 never touches HBM; by
// linearity agg(Wl2.h2) = Wl2.agg(h2) so the projection precedes the gather).
// A latency hidden by upfront 16-load ILP (as in k_gemm_mfma).
// Phase B: P = h2.Wl2^T, R = h2.Wr2^T + b2.
// LDS reuse: Ws (128x264) overwritten after barrier by h2L (stride 140) +
// W2L (stride 136) -- both <=2-way bank patterns.
__global__ __launch_bounds__(256) void k_gemm12(
    const ushort* __restrict__ A,       // AbufB: [agg(h1) | h1], stride 256
    const ushort* __restrict__ Wt1,     // [128][256] bf16
    const float* __restrict__ b1,
    const ushort* __restrict__ W2,      // [80][128] bf16 (Wl2 rows 0-39, Wr2 rows 40-79)
    const float* __restrict__ b2,
    ushort* __restrict__ P,             // [N,40]
    ushort* __restrict__ R,             // [N,40]
    int nN)
{
    constexpr int SW = 264, H2S = 140, W2S = 136, W2OFF = 128 * H2S;
    __shared__ __align__(16) ushort Ws[128 * SW];

    const int tid = threadIdx.x;
    const int l = tid & 63, wv = tid >> 6;
    const int q = l >> 4, r = l & 15;
    const long long m0 = (long long)blockIdx.x * 128 + wv * 32;
    const int mA = (int)min(m0 + r, (long long)(nN - 1));
    const int mB = (int)min(m0 + 16 + r, (long long)(nN - 1));
    const ushort* pa = A + (size_t)mA * 256 + q * 8;
    const ushort* pb = A + (size_t)mB * 256 + q * 8;

    // issue ALL A-loads first: 16 independent dwordx4 in flight
    bf16x8 aR0[8], aR1[8];
#pragma unroll
    for (int ks = 0; ks < 8; ++ks) {
        aR0[ks] = *(const bf16x8*)(pa + ks * 32);
        aR1[ks] = *(const bf16x8*)(pb + ks * 32);
    }

#pragma unroll
    for (int c = tid; c < 128 * 32; c += 256) {
        int row = c >> 5;
        int ko  = (c & 31) * 8;
        *(uint4*)(Ws + row * SW + ko) = *(const uint4*)(Wt1 + row * 256 + ko);
    }
    __syncthreads();

    f32x4 acc[2][8];
#pragma unroll
    for (int mt = 0; mt < 2; ++mt)
#pragma unroll
        for (int nt = 0; nt < 8; ++nt)
            acc[mt][nt] = (f32x4){0.f, 0.f, 0.f, 0.f};

#pragma unroll
    for (int ks = 0; ks < 8; ++ks) {
#pragma unroll
        for (int nt = 0; nt < 8; ++nt) {
            bf16x8 b = *(const bf16x8*)(Ws + (nt * 16 + r) * SW + ks * 32 + q * 8);
            acc[0][nt] = __builtin_amdgcn_mfma_f32_16x16x32_bf16(aR0[ks], b, acc[0][nt], 0, 0, 0);
            acc[1][nt] = __builtin_amdgcn_mfma_f32_16x16x32_bf16(aR1[ks], b, acc[1][nt], 0, 0, 0);
        }
    }
    __syncthreads();            // all waves done reading Ws

    // write h2 (bias+relu, bf16) into LDS; stage W2
#pragma unroll
    for (int mt = 0; mt < 2; ++mt)
#pragma unroll
        for (int i = 0; i < 4; ++i) {
            int row = wv * 32 + mt * 16 + q * 4 + i;
#pragma unroll
            for (int nt = 0; nt < 8; ++nt) {
                int cc = nt * 16 + r;
                float v = acc[mt][nt][i] + b1[cc];
                Ws[row * H2S + cc] = f2b(fmaxf(v, 0.f));
            }
        }
#pragma unroll
    for (int c = tid; c < 80 * 16; c += 256) {
        int row = c >> 4;
        int ko  = (c & 15) * 8;
        *(uint4*)(Ws + W2OFF + row * W2S + ko) = *(const uint4*)(W2 + row * 128 + ko);
    }
    __syncthreads();

    // phase B: (128x128 h2) x (80x128 W2)^T
    f32x4 acc2[2][5];
#pragma unroll
    for (int mt = 0; mt < 2; ++mt)
#pragma unroll
        for (int nt = 0; nt < 5; ++nt)
            acc2[mt][nt] = (f32x4){0.f, 0.f, 0.f, 0.f};

#pragma unroll
    for (int ks = 0; ks < 4; ++ks) {
        bf16x8 a0b = *(const bf16x8*)(Ws + (wv * 32 + r) * H2S + ks * 32 + q * 8);
        bf16x8 a1b = *(const bf16x8*)(Ws + (wv * 32 + 16 + r) * H2S + ks * 32 + q * 8);
#pragma unroll
        for (int nt = 0; nt < 5; ++nt) {
            bf16x8 b = *(const bf16x8*)(Ws + W2OFF + (nt * 16 + r) * W2S + ks * 32 + q * 8);
            acc2[0][nt] = __builtin_amdgcn_mfma_f32_16x16x32_bf16(a0b, b, acc2[0][nt], 0, 0, 0);
            acc2[1][nt] = __builtin_amdgcn_mfma_f32_16x16x32_bf16(a1b, b, acc2[1][nt], 0, 0, 0);
        }
    }

#pragma unroll
    for (int mt = 0; mt < 2; ++mt) {
#pragma unroll
        for (int i = 0; i < 4; ++i) {
            long long m = m0 + mt * 16 + q * 4 + i;
            if (m >= nN) continue;
#pragma unroll
            for (int nt = 0; nt < 5; ++nt) {
                int cc = nt * 16 + r;
                float v = acc2[mt][nt][i];
                if (cc < 40) P[(size_t)m * 40 + cc] = f2b(v);
                else { v += b2[cc - 40]; R[(size_t)m * 40 + (cc - 40)] = f2b(v); }
            }
        }
    }
}

// ---------------------------------------------------------------- 40-dim mean-gather + self + log_softmax
// 4 nodes per wave: h=lane>>4, 2 edge slots x 8 chunks of 16B (r>=5 reads spill
// into next row: finite garbage, masked at softmax).
__global__ __launch_bounds__(256) void k_gather40_lsm(
    const ushort* __restrict__ P, const ushort* __restrict__ R,
    const int* __restrict__ rowptr, const int* __restrict__ col,
    float* __restrict__ out, int nN)
{
    int tid = threadIdx.x;
    int lane = tid & 63;
    int h = lane >> 4;          // node sub 0..3
    int node = blockIdx.x * 16 + ((tid >> 6) << 2) + h;
    if (node >= nN) return;
    int g = (lane >> 3) & 1;    // edge slot 0..1
    int r = lane & 7;           // 16B chunk -> cols 8r..8r+7 (valid r<5)
    int beg = rowptr[node], end = rowptr[node + 1];
    const char* pbase = (const char*)P;
    const uint rb = (uint)(r << 4);
    f32x2 a2[4];
#pragma unroll
    for (int i = 0; i < 4; ++i) a2[i] = (f32x2){0.f, 0.f};

    int j = beg + g;
    for (; j + 2 < end; j += 4) {          // 4 edges/node per unrolled iter
        int s0 = col[j], s1 = col[j + 2];
        uint4 v0 = *(const uint4*)(pbase + ((((uint)s0 * 5u) << 4) + rb));
        uint4 v1 = *(const uint4*)(pbase + ((((uint)s1 * 5u) << 4) + rb));
        const uint* p0 = (const uint*)&v0;
        const uint* p1 = (const uint*)&v1;
#pragma unroll
        for (int i = 0; i < 4; ++i)
            a2[i] += (f32x2){blo(p0[i]) + blo(p1[i]), bhi(p0[i]) + bhi(p1[i])};
    }
    if (j < end) {
        int s0 = col[j];
        uint4 v0 = *(const uint4*)(pbase + ((((uint)s0 * 5u) << 4) + rb));
        const uint* p0 = (const uint*)&v0;
#pragma unroll
        for (int i = 0; i < 4; ++i)
            a2[i] += (f32x2){blo(p0[i]), bhi(p0[i])};
    }
    float a[8];
#pragma unroll
    for (int i = 0; i < 4; ++i) { a[2 * i] = a2[i].x; a[2 * i + 1] = a2[i].y; }
#pragma unroll
    for (int i = 0; i < 8; ++i)
        a[i] += __shfl_xor(a[i], 8);       // reduce across the 2 slots
    float inv = 1.0f / (float)max(end - beg, 1);
    uint4 rv = *(const uint4*)(R + (size_t)node * 40 + r * 8);
    const uint* pr = (const uint*)&rv;
    float vv[8];
    float mx = -INFINITY;
#pragma unroll
    for (int i = 0; i < 8; ++i) {
        float rc = (i & 1) ? bhi(pr[i >> 1]) : blo(pr[i >> 1]);
        int c = r * 8 + i;
        vv[i] = (c < 40) ? (a[i] * inv + rc) : -INFINITY;
        mx = fmaxf(mx, vv[i]);
    }
    mx = fmaxf(mx, __shfl_xor(mx, 1));
    mx = fmaxf(mx, __shfl_xor(mx, 2));
    mx = fmaxf(mx, __shfl_xor(mx, 4));
    float s = 0.f;
#pragma unroll
    for (int i = 0; i < 8; ++i) {
        int c = r * 8 + i;
        if (c < 40) s += __expf(vv[i] - mx);
    }
    s += __shfl_xor(s, 1);
    s += __shfl_xor(s, 2);
    s += __shfl_xor(s, 4);
    float lse = mx + __logf(s);
    if (g == 0 && r < 5) {
        float4 o0 = make_float4(vv[0] - lse, vv[1] - lse, vv[2] - lse, vv[3] - lse);
        float4 o1 = make_float4(vv[4] - lse, vv[5] - lse, vv[6] - lse, vv[7] - lse);
        *(float4*)(out + (size_t)node * 40 + r * 8)     = o0;
        *(float4*)(out + (size_t)node * 40 + r * 8 + 4) = o1;
    }
}

// ---------------------------------------------------------------- launch
extern "C" void kernel_launch(void* const* d_in, const int* in_sizes, int n_in,
                              void* d_out, int out_size, void* d_ws, size_t ws_size,
                              hipStream_t stream) {
    const float* x   = (const float*)d_in[0];
    const int*   ei  = (const int*)d_in[1];
    const float* Wl0 = (const float*)d_in[2];
    const float* Wr0 = (const float*)d_in[3];
    const float* b0  = (const float*)d_in[4];
    const float* Wl1 = (const float*)d_in[5];
    const float* Wr1 = (const float*)d_in[6];
    const float* b1  = (const float*)d_in[7];
    const float* Wl2 = (const float*)d_in[8];
    const float* Wr2 = (const float*)d_in[9];
    const float* b2  = (const float*)d_in[10];
    const int nN = in_sizes[0] / D;
    const int E  = in_sizes[1] / 2;
    const int* src = ei;
    const int* dst = ei + E;

    char* w = (char*)d_ws;
    auto alloc = [&](size_t bytes) { char* p = w; w += (bytes + 255) & ~(size_t)255; return p; };
    const int nbuck = (nN + 1023) >> 10;
    const int ncnt  = nbuck * NBLK_A;
    int*    cnt    = (int*)   alloc((size_t)ncnt * 4);
    int*    bsum   = (int*)   alloc((size_t)((ncnt + 255) / 256) * 4);
    int*    bb     = (int*)   alloc((size_t)(nbuck + 1) * 4);
    int*    rowptr = (int*)   alloc((size_t)(nN + 1) * 4);
    int*    col    = (int*)   alloc((size_t)E * 4);
    ushort* AbufA  = (ushort*)alloc((size_t)nN * 256 * 2);    // [agg | feat] bf16
    ushort* AbufB  = (ushort*)alloc((size_t)nN * 256 * 2);
    ushort* Wtg0   = (ushort*)alloc((size_t)128 * 256 * 2);
    ushort* Wtg1   = (ushort*)alloc((size_t)128 * 256 * 2);
    ushort* W2tg   = (ushort*)alloc((size_t)80 * 128 * 2);
    // ebuf aliases AbufB: dead after k_bfine, first AbufB write is layer-0 GEMM
    uint*   ebuf   = (uint*)AbufB;
    // P/R alias into AbufA (fully dead after layer-1 gather reads AbufB)
    ushort* Pbuf   = AbufA;                    // [N,40] bf16 packed
    ushort* Rbuf   = AbufA + (size_t)nN * 40;  // [N,40] bf16
    float*  logits = (float*)d_out;

    const int GATH_BLKS = (nN + 7) / 8;        // 8 nodes per block (2 per wave)
    const int G40_BLKS  = (nN + 15) / 16;      // 16 nodes per block (4 per wave)
    const int GEMM_BLKS = (nN + 127) / 128;
    const int n4        = nN * 32;
    const int NBSC      = (ncnt + 255) / 256;

    // ---- CSR build (LDS-atomic bucket sort, parallel scan) + cast + weight prep
    k_bcount<<<NBLK_A, 256, 0, stream>>>(dst, cnt, E, nbuck, x, AbufA, n4,
                                         Wl0, Wr0, Wl1, Wr1, Wl2, Wr2,
                                         Wtg0, Wtg1, W2tg);
    k_scanA <<<NBSC, 256, 0, stream>>>(cnt, bsum, ncnt);
    k_scan2 <<<1, 512, 0, stream>>>(bsum, NBSC, bb, nbuck, E);
    k_bplace<<<NBLK_A, 256, 0, stream>>>(src, dst, cnt, bsum, ebuf, E, nbuck);
    k_bfine <<<nbuck, 1024, 0, stream>>>(ebuf, bb, rowptr, col, nN, nbuck, E);

    // ---- layer 0
    k_gather128<<<GATH_BLKS, 256, 0, stream>>>(AbufA + 128, AbufA, rowptr, col, nN);
    k_gemm_mfma<<<GEMM_BLKS, 256, 0, stream>>>(
        AbufA, 256, Wtg0, b0, AbufB + 128, 256, nN);

    // ---- layer 1 gather, then fused layer-1 GEMM + layer-2 projection
    k_gather128<<<GATH_BLKS, 256, 0, stream>>>(AbufB + 128, AbufB, rowptr, col, nN);
    k_gemm12<<<GEMM_BLKS, 256, 0, stream>>>(
        AbufB, Wtg1, b1, W2tg, b2, Pbuf, Rbuf, nN);

    // ---- 40-dim gather + log_softmax
    k_gather40_lsm<<<G40_BLKS, 256, 0, stream>>>(Pbuf, Rbuf, rowptr, col, logits, nN);
}

// Round 13
// 286.389 us; speedup vs baseline: 1.0247x; 1.0247x over previous
//
#include <hip/hip_runtime.h>
#include <hip/hip_bf16.h>
#include <math.h>

#define D 128
typedef unsigned int uint;
typedef unsigned short ushort;

using bf16x8 = __attribute__((ext_vector_type(8))) short;
using f32x4  = __attribute__((ext_vector_type(4))) float;
using f32x2  = __attribute__((ext_vector_type(2))) float;

static __device__ __forceinline__ ushort f2b(float f) {
    __hip_bfloat16 h = __float2bfloat16(f);
    return __builtin_bit_cast(ushort, h);
}
static __device__ __forceinline__ float blo(uint u) {
    uint v = u << 16;
    return __builtin_bit_cast(float, v);
}
static __device__ __forceinline__ float bhi(uint u) {
    uint v = u & 0xFFFF0000u;
    return __builtin_bit_cast(float, v);
}

#define NBLK_A 1024     // blocks for coarse count/place passes
#define MAXB   128      // max coarse buckets (nN <= 128K)
#define WTOT   (2*128*256 + 80*128)

// ---------------------------------------------------------------- pass A
// Coarse LDS histogram (bucket = dst>>10) per block chunk + fused cast/weights.
__global__ __launch_bounds__(256) void k_bcount(
    const int* __restrict__ dst, int* __restrict__ cnt, int E, int nbuck,
    const float* __restrict__ x, ushort* __restrict__ Abuf, int n4,
    const float* __restrict__ Wl0, const float* __restrict__ Wr0,
    const float* __restrict__ Wl1, const float* __restrict__ Wr1,
    const float* __restrict__ Wl2, const float* __restrict__ Wr2,
    ushort* __restrict__ Wtg0, ushort* __restrict__ Wtg1,
    ushort* __restrict__ W2tg)
{
    __shared__ int h[MAXB];
    int tid = threadIdx.x, b = blockIdx.x;
    for (int k = tid; k < nbuck; k += 256) h[k] = 0;
    __syncthreads();
    int chunk = (E + NBLK_A - 1) / NBLK_A;
    int beg = b * chunk, end = min(beg + chunk, E);
    for (int e = beg + tid; e < end; e += 256)
        atomicAdd(&h[dst[e] >> 10], 1);
    __syncthreads();
    for (int k = tid; k < nbuck; k += 256) cnt[k * NBLK_A + b] = h[k];

    // fused bf16 cast of x into AbufA cols 128..255
    for (int i = b * 256 + tid; i < n4; i += NBLK_A * 256) {
        float4 v = *(const float4*)(x + (size_t)i * 4);
        int node = i >> 5, coff = (i & 31) * 4;
        ushort4 o;
        o.x = f2b(v.x); o.y = f2b(v.y); o.z = f2b(v.z); o.w = f2b(v.w);
        *(ushort4*)(Abuf + (size_t)node * 256 + 128 + coff) = o;
    }
    // fused weight prep
    for (int i = b * 256 + tid; i < WTOT; i += NBLK_A * 256) {
        if (i < 2 * 128 * 256) {
            int which = i >> 15;
            int o = i & 32767;
            int j = o >> 8, kk = o & 255;
            const float* Wl = which ? Wl1 : Wl0;
            const float* Wr = which ? Wr1 : Wr0;
            float v = (kk < 128) ? Wl[j * 128 + kk] : Wr[j * 128 + (kk - 128)];
            (which ? Wtg1 : Wtg0)[o] = f2b(v);
        } else {
            int o = i - 2 * 128 * 256;
            int j = o >> 7, kk = o & 127;
            float v = (j < 40) ? Wl2[j * 128 + kk] : Wr2[(j - 40) * 128 + kk];
            W2tg[o] = f2b(v);
        }
    }
}

// ---------------------------------------------------------------- hierarchical scan
__global__ __launch_bounds__(256) void k_scanA(int* __restrict__ a,
                                               int* __restrict__ bsum, int n) {
    __shared__ int s[256];
    int tid = threadIdx.x;
    int i = blockIdx.x * 256 + tid;
    int v = (i < n) ? a[i] : 0;
    s[tid] = v;
    __syncthreads();
#pragma unroll
    for (int o = 1; o < 256; o <<= 1) {
        int t = (tid >= o) ? s[tid - o] : 0;
        __syncthreads();
        s[tid] += t;
        __syncthreads();
    }
    if (i < n) a[i] = s[tid] - v;
    if (tid == 255) bsum[blockIdx.x] = s[255];
}

// scan of block sums + bucket-base extraction.
__global__ void k_scan2(int* __restrict__ bsum, int nb,
                        int* __restrict__ bb, int nbuck, int E) {
    __shared__ int s[512];
    __shared__ int carry_s;
    int tid = threadIdx.x;
    if (tid == 0) carry_s = 0;
    __syncthreads();
    for (int base = 0; base < nb; base += 512) {
        int i = base + tid;
        int v = (i < nb) ? bsum[i] : 0;
        s[tid] = v;
        __syncthreads();
#pragma unroll
        for (int o = 1; o < 512; o <<= 1) {
            int t = (tid >= o) ? s[tid - o] : 0;
            __syncthreads();
            s[tid] += t;
            __syncthreads();
        }
        int carry = carry_s;
        if (i < nb) bsum[i] = s[tid] - v + carry;
        int total = s[511];
        __syncthreads();
        if (tid == 0) carry_s = carry + total;
        __syncthreads();
    }
    for (int k = tid; k < nbuck; k += 512) bb[k] = bsum[k * (NBLK_A >> 8)];
    if (tid == 0) bb[nbuck] = E;
}

// ---------------------------------------------------------------- pass C
// ebuf packed: src in bits 0..19, fine bin (dst&1023) in bits 20..29.
__global__ __launch_bounds__(256) void k_bplace(
    const int* __restrict__ src, const int* __restrict__ dst,
    const int* __restrict__ cnt, const int* __restrict__ bsum,
    uint* __restrict__ ebuf, int E, int nbuck)
{
    __shared__ int cur[MAXB];
    int tid = threadIdx.x, b = blockIdx.x;
    for (int k = tid; k < nbuck; k += 256) {
        int idx = k * NBLK_A + b;
        cur[k] = cnt[idx] + bsum[idx >> 8];
    }
    __syncthreads();
    int chunk = (E + NBLK_A - 1) / NBLK_A;
    int beg = b * chunk, end = min(beg + chunk, E);
    for (int e = beg + tid; e < end; e += 256) {
        int d = dst[e];
        int r = atomicAdd(&cur[d >> 10], 1);
        ebuf[r] = (uint)src[e] | ((uint)(d & 1023) << 20);
    }
}

// ---------------------------------------------------------------- pass D
__global__ __launch_bounds__(1024) void k_bfine(
    const uint* __restrict__ ebuf, const int* __restrict__ bb,
    int* __restrict__ rowptr, int* __restrict__ col, int nN, int nbuck, int E)
{
    __shared__ int cnt2[1024];
    __shared__ int sc[1024];
    int k = blockIdx.x, tid = threadIdx.x;
    int e0 = bb[k], e1 = bb[k + 1];
    cnt2[tid] = 0;
    __syncthreads();
    for (int e = e0 + tid; e < e1; e += 1024)
        atomicAdd(&cnt2[ebuf[e] >> 20], 1);
    __syncthreads();
    int v = cnt2[tid];
    sc[tid] = v;
    __syncthreads();
#pragma unroll
    for (int o = 1; o < 1024; o <<= 1) {
        int t = (tid >= o) ? sc[tid - o] : 0;
        __syncthreads();
        sc[tid] += t;
        __syncthreads();
    }
    int excl = sc[tid] - v;
    int node = k * 1024 + tid;
    if (node < nN) rowptr[node] = e0 + excl;
    if (k == nbuck - 1 && tid == 0) rowptr[nN] = E;
    cnt2[tid] = e0 + excl;       // reuse as cursor
    __syncthreads();
    for (int e = e0 + tid; e < e1; e += 1024) {
        uint sd = ebuf[e];
        int r = atomicAdd(&cnt2[sd >> 20], 1);
        col[r] = (int)(sd & 0xFFFFFu);
    }
}

// ---------------------------------------------------------------- 128-dim mean-gather
// 2 nodes per wave: h=lane>>5 picks node, 2 edge slots x 16 chunks of 16B.
__global__ __launch_bounds__(256) void k_gather128(
    const ushort* __restrict__ feat, ushort* __restrict__ agg,
    const int* __restrict__ rowptr, const int* __restrict__ col, int nN)
{
    int tid = threadIdx.x;
    int lane = tid & 63;
    int h = lane >> 5;
    int node = blockIdx.x * 8 + ((tid >> 6) << 1) + h;
    if (node >= nN) return;
    int g = (lane >> 4) & 1;    // edge slot 0..1
    int r = lane & 15;          // 16B chunk -> cols 8r..8r+7
    int beg = rowptr[node], end = rowptr[node + 1];
    const char* fb = (const char*)feat;
    const uint rb = (uint)(r << 4);
    float a[8];
#pragma unroll
    for (int i = 0; i < 8; ++i) a[i] = 0.f;

    int j = beg + g;
    for (; j + 2 < end; j += 4) {          // 4 edges/node per unrolled iter
        int s0 = col[j], s1 = col[j + 2];
        uint4 v0 = *(const uint4*)(fb + (((uint)s0 << 9) + rb));
        uint4 v1 = *(const uint4*)(fb + (((uint)s1 << 9) + rb));
        const uint* p0 = (const uint*)&v0;
        const uint* p1 = (const uint*)&v1;
#pragma unroll
        for (int i = 0; i < 4; ++i) {
            a[2 * i]     += blo(p0[i]) + blo(p1[i]);
            a[2 * i + 1] += bhi(p0[i]) + bhi(p1[i]);
        }
    }
    if (j < end) {
        int s0 = col[j];
        uint4 v0 = *(const uint4*)(fb + (((uint)s0 << 9) + rb));
        const uint* p0 = (const uint*)&v0;
#pragma unroll
        for (int i = 0; i < 4; ++i) {
            a[2 * i]     += blo(p0[i]);
            a[2 * i + 1] += bhi(p0[i]);
        }
    }
#pragma unroll
    for (int i = 0; i < 8; ++i)
        a[i] += __shfl_xor(a[i], 16);      // reduce across the 2 slots
    if (g == 0) {
        float inv = 1.0f / (float)max(end - beg, 1);
        uint4 o;
        uint* po = (uint*)&o;
#pragma unroll
        for (int i = 0; i < 4; ++i)
            po[i] = (uint)f2b(a[2 * i] * inv) | ((uint)f2b(a[2 * i + 1] * inv) << 16);
        *(uint4*)(agg + (size_t)node * 256 + r * 8) = o;
    }
}

// ---------------------------------------------------------------- MFMA GEMM (layer 0)
// Full-K weight tile (66 KB LDS), prefetch-1-ahead A loads (round-10 best).
__global__ __launch_bounds__(256) void k_gemm_mfma(
    const ushort* __restrict__ A, int astride,
    const ushort* __restrict__ Wt, const float* __restrict__ bias,
    ushort* __restrict__ out, int ostride, int nN)
{
    constexpr int SW = 264;
    __shared__ __align__(16) ushort Ws[128 * SW];

    const int tid = threadIdx.x;
#pragma unroll
    for (int c = tid; c < 128 * 32; c += 256) {
        int row = c >> 5;
        int ko  = (c & 31) * 8;
        *(uint4*)(Ws + row * SW + ko) = *(const uint4*)(Wt + row * 256 + ko);
    }
    __syncthreads();

    const int l = tid & 63, wv = tid >> 6;
    const int q = l >> 4, r = l & 15;
    const long long m0 = (long long)blockIdx.x * 128 + wv * 32;
    const int mA = (int)min(m0 + r, (long long)(nN - 1));
    const int mB = (int)min(m0 + 16 + r, (long long)(nN - 1));
    const ushort* pa = A + (size_t)mA * astride + q * 8;
    const ushort* pb = A + (size_t)mB * astride + q * 8;

    f32x4 acc[2][8];
#pragma unroll
    for (int mt = 0; mt < 2; ++mt)
#pragma unroll
        for (int nt = 0; nt < 8; ++nt)
            acc[mt][nt] = (f32x4){0.f, 0.f, 0.f, 0.f};

    bf16x8 a0 = *(const bf16x8*)pa;
    bf16x8 a1 = *(const bf16x8*)pb;
#pragma unroll
    for (int ks = 0; ks < 8; ++ks) {
        bf16x8 a0n = a0, a1n = a1;
        if (ks + 1 < 8) {
            a0n = *(const bf16x8*)(pa + (ks + 1) * 32);
            a1n = *(const bf16x8*)(pb + (ks + 1) * 32);
        }
#pragma unroll
        for (int nt = 0; nt < 8; ++nt) {
            bf16x8 b = *(const bf16x8*)(Ws + (nt * 16 + r) * SW + ks * 32 + q * 8);
            acc[0][nt] = __builtin_amdgcn_mfma_f32_16x16x32_bf16(a0, b, acc[0][nt], 0, 0, 0);
            acc[1][nt] = __builtin_amdgcn_mfma_f32_16x16x32_bf16(a1, b, acc[1][nt], 0, 0, 0);
        }
        a0 = a0n; a1 = a1n;
    }

#pragma unroll
    for (int mt = 0; mt < 2; ++mt) {
#pragma unroll
        for (int i = 0; i < 4; ++i) {
            long long m = m0 + mt * 16 + q * 4 + i;
            if (m >= nN) continue;
#pragma unroll
            for (int nt = 0; nt < 8; ++nt) {
                int cc = nt * 16 + r;
                float v = acc[mt][nt][i] + bias[cc];
                v = fmaxf(v, 0.f);
                out[(size_t)m * ostride + cc] = f2b(v);
            }
        }
    }
}

// ---------------------------------------------------------------- fused layer-1 GEMM + layer-2 projection
// Phase A: h2 = relu(A.Wt1 + b1) kept in LDS only (h2 never touches HBM; by
// linearity agg(Wl2.h2) = Wl2.agg(h2) so the projection can precede the gather).
// Phase B: P = h2.Wl2^T, R = h2.Wr2^T + b2.
// LDS reuse: Ws (128x264, phase-A weights) is overwritten after a barrier by
// h2L (stride 140: ds_write q-groups land on banks 0/24/16/8, <=2-way; reads
// advance 6 banks/row, conflict-free) + W2L (stride 136, 2-way free).
__global__ __launch_bounds__(256) void k_gemm12(
    const ushort* __restrict__ A,       // AbufB: [agg(h1) | h1], stride 256
    const ushort* __restrict__ Wt1,     // [128][256] bf16
    const float* __restrict__ b1,
    const ushort* __restrict__ W2,      // [80][128] bf16 (Wl2 rows 0-39, Wr2 rows 40-79)
    const float* __restrict__ b2,
    ushort* __restrict__ P,             // [N,40]
    ushort* __restrict__ R,             // [N,40]
    int nN)
{
    constexpr int SW = 264, H2S = 140, W2S = 136, W2OFF = 128 * H2S;
    __shared__ __align__(16) ushort Ws[128 * SW];

    const int tid = threadIdx.x;
#pragma unroll
    for (int c = tid; c < 128 * 32; c += 256) {
        int row = c >> 5;
        int ko  = (c & 31) * 8;
        *(uint4*)(Ws + row * SW + ko) = *(const uint4*)(Wt1 + row * 256 + ko);
    }
    __syncthreads();

    const int l = tid & 63, wv = tid >> 6;
    const int q = l >> 4, r = l & 15;
    const long long m0 = (long long)blockIdx.x * 128 + wv * 32;
    const int mA = (int)min(m0 + r, (long long)(nN - 1));
    const int mB = (int)min(m0 + 16 + r, (long long)(nN - 1));
    const ushort* pa = A + (size_t)mA * 256 + q * 8;
    const ushort* pb = A + (size_t)mB * 256 + q * 8;

    f32x4 acc[2][8];
#pragma unroll
    for (int mt = 0; mt < 2; ++mt)
#pragma unroll
        for (int nt = 0; nt < 8; ++nt)
            acc[mt][nt] = (f32x4){0.f, 0.f, 0.f, 0.f};

    bf16x8 a0 = *(const bf16x8*)pa;
    bf16x8 a1 = *(const bf16x8*)pb;
#pragma unroll
    for (int ks = 0; ks < 8; ++ks) {
        bf16x8 a0n = a0, a1n = a1;
        if (ks + 1 < 8) {
            a0n = *(const bf16x8*)(pa + (ks + 1) * 32);
            a1n = *(const bf16x8*)(pb + (ks + 1) * 32);
        }
#pragma unroll
        for (int nt = 0; nt < 8; ++nt) {
            bf16x8 b = *(const bf16x8*)(Ws + (nt * 16 + r) * SW + ks * 32 + q * 8);
            acc[0][nt] = __builtin_amdgcn_mfma_f32_16x16x32_bf16(a0, b, acc[0][nt], 0, 0, 0);
            acc[1][nt] = __builtin_amdgcn_mfma_f32_16x16x32_bf16(a1, b, acc[1][nt], 0, 0, 0);
        }
        a0 = a0n; a1 = a1n;
    }
    __syncthreads();            // all waves done reading Ws

    // write h2 (bias+relu, bf16) into LDS; stage W2
#pragma unroll
    for (int mt = 0; mt < 2; ++mt)
#pragma unroll
        for (int i = 0; i < 4; ++i) {
            int row = wv * 32 + mt * 16 + q * 4 + i;
#pragma unroll
            for (int nt = 0; nt < 8; ++nt) {
                int cc = nt * 16 + r;
                float v = acc[mt][nt][i] + b1[cc];
                Ws[row * H2S + cc] = f2b(fmaxf(v, 0.f));
            }
        }
#pragma unroll
    for (int c = tid; c < 80 * 16; c += 256) {
        int row = c >> 4;
        int ko  = (c & 15) * 8;
        *(uint4*)(Ws + W2OFF + row * W2S + ko) = *(const uint4*)(W2 + row * 128 + ko);
    }
    __syncthreads();

    // phase B: (128x128 h2) x (80x128 W2)^T
    f32x4 acc2[2][5];
#pragma unroll
    for (int mt = 0; mt < 2; ++mt)
#pragma unroll
        for (int nt = 0; nt < 5; ++nt)
            acc2[mt][nt] = (f32x4){0.f, 0.f, 0.f, 0.f};

#pragma unroll
    for (int ks = 0; ks < 4; ++ks) {
        bf16x8 a0b = *(const bf16x8*)(Ws + (wv * 32 + r) * H2S + ks * 32 + q * 8);
        bf16x8 a1b = *(const bf16x8*)(Ws + (wv * 32 + 16 + r) * H2S + ks * 32 + q * 8);
#pragma unroll
        for (int nt = 0; nt < 5; ++nt) {
            bf16x8 b = *(const bf16x8*)(Ws + W2OFF + (nt * 16 + r) * W2S + ks * 32 + q * 8);
            acc2[0][nt] = __builtin_amdgcn_mfma_f32_16x16x32_bf16(a0b, b, acc2[0][nt], 0, 0, 0);
            acc2[1][nt] = __builtin_amdgcn_mfma_f32_16x16x32_bf16(a1b, b, acc2[1][nt], 0, 0, 0);
        }
    }

#pragma unroll
    for (int mt = 0; mt < 2; ++mt) {
#pragma unroll
        for (int i = 0; i < 4; ++i) {
            long long m = m0 + mt * 16 + q * 4 + i;
            if (m >= nN) continue;
#pragma unroll
            for (int nt = 0; nt < 5; ++nt) {
                int cc = nt * 16 + r;
                float v = acc2[mt][nt][i];
                if (cc < 40) P[(size_t)m * 40 + cc] = f2b(v);
                else { v += b2[cc - 40]; R[(size_t)m * 40 + (cc - 40)] = f2b(v); }
            }
        }
    }
}

// ---------------------------------------------------------------- 40-dim mean-gather + self + log_softmax
// 4 nodes per wave: h=lane>>4, 2 edge slots x 8 chunks of 16B (r>=5 reads spill
// into next row: finite garbage, masked at softmax).
__global__ __launch_bounds__(256) void k_gather40_lsm(
    const ushort* __restrict__ P, const ushort* __restrict__ R,
    const int* __restrict__ rowptr, const int* __restrict__ col,
    float* __restrict__ out, int nN)
{
    int tid = threadIdx.x;
    int lane = tid & 63;
    int h = lane >> 4;          // node sub 0..3
    int node = blockIdx.x * 16 + ((tid >> 6) << 2) + h;
    if (node >= nN) return;
    int g = (lane >> 3) & 1;    // edge slot 0..1
    int r = lane & 7;           // 16B chunk -> cols 8r..8r+7 (valid r<5)
    int beg = rowptr[node], end = rowptr[node + 1];
    const char* pbase = (const char*)P;
    const uint rb = (uint)(r << 4);
    f32x2 a2[4];
#pragma unroll
    for (int i = 0; i < 4; ++i) a2[i] = (f32x2){0.f, 0.f};

    int j = beg + g;
    for (; j + 2 < end; j += 4) {          // 4 edges/node per unrolled iter
        int s0 = col[j], s1 = col[j + 2];
        uint4 v0 = *(const uint4*)(pbase + ((((uint)s0 * 5u) << 4) + rb));
        uint4 v1 = *(const uint4*)(pbase + ((((uint)s1 * 5u) << 4) + rb));
        const uint* p0 = (const uint*)&v0;
        const uint* p1 = (const uint*)&v1;
#pragma unroll
        for (int i = 0; i < 4; ++i)
            a2[i] += (f32x2){blo(p0[i]) + blo(p1[i]), bhi(p0[i]) + bhi(p1[i])};
    }
    if (j < end) {
        int s0 = col[j];
        uint4 v0 = *(const uint4*)(pbase + ((((uint)s0 * 5u) << 4) + rb));
        const uint* p0 = (const uint*)&v0;
#pragma unroll
        for (int i = 0; i < 4; ++i)
            a2[i] += (f32x2){blo(p0[i]), bhi(p0[i])};
    }
    float a[8];
#pragma unroll
    for (int i = 0; i < 4; ++i) { a[2 * i] = a2[i].x; a[2 * i + 1] = a2[i].y; }
#pragma unroll
    for (int i = 0; i < 8; ++i)
        a[i] += __shfl_xor(a[i], 8);       // reduce across the 2 slots
    float inv = 1.0f / (float)max(end - beg, 1);
    uint4 rv = *(const uint4*)(R + (size_t)node * 40 + r * 8);
    const uint* pr = (const uint*)&rv;
    float vv[8];
    float mx = -INFINITY;
#pragma unroll
    for (int i = 0; i < 8; ++i) {
        float rc = (i & 1) ? bhi(pr[i >> 1]) : blo(pr[i >> 1]);
        int c = r * 8 + i;
        vv[i] = (c < 40) ? (a[i] * inv + rc) : -INFINITY;
        mx = fmaxf(mx, vv[i]);
    }
    mx = fmaxf(mx, __shfl_xor(mx, 1));
    mx = fmaxf(mx, __shfl_xor(mx, 2));
    mx = fmaxf(mx, __shfl_xor(mx, 4));
    float s = 0.f;
#pragma unroll
    for (int i = 0; i < 8; ++i) {
        int c = r * 8 + i;
        if (c < 40) s += __expf(vv[i] - mx);
    }
    s += __shfl_xor(s, 1);
    s += __shfl_xor(s, 2);
    s += __shfl_xor(s, 4);
    float lse = mx + __logf(s);
    if (g == 0 && r < 5) {
        float4 o0 = make_float4(vv[0] - lse, vv[1] - lse, vv[2] - lse, vv[3] - lse);
        float4 o1 = make_float4(vv[4] - lse, vv[5] - lse, vv[6] - lse, vv[7] - lse);
        *(float4*)(out + (size_t)node * 40 + r * 8)     = o0;
        *(float4*)(out + (size_t)node * 40 + r * 8 + 4) = o1;
    }
}

// ---------------------------------------------------------------- launch
extern "C" void kernel_launch(void* const* d_in, const int* in_sizes, int n_in,
                              void* d_out, int out_size, void* d_ws, size_t ws_size,
                              hipStream_t stream) {
    const float* x   = (const float*)d_in[0];
    const int*   ei  = (const int*)d_in[1];
    const float* Wl0 = (const float*)d_in[2];
    const float* Wr0 = (const float*)d_in[3];
    const float* b0  = (const float*)d_in[4];
    const float* Wl1 = (const float*)d_in[5];
    const float* Wr1 = (const float*)d_in[6];
    const float* b1  = (const float*)d_in[7];
    const float* Wl2 = (const float*)d_in[8];
    const float* Wr2 = (const float*)d_in[9];
    const float* b2  = (const float*)d_in[10];
    const int nN = in_sizes[0] / D;
    const int E  = in_sizes[1] / 2;
    const int* src = ei;
    const int* dst = ei + E;

    char* w = (char*)d_ws;
    auto alloc = [&](size_t bytes) { char* p = w; w += (bytes + 255) & ~(size_t)255; return p; };
    const int nbuck = (nN + 1023) >> 10;
    const int ncnt  = nbuck * NBLK_A;
    int*    cnt    = (int*)   alloc((size_t)ncnt * 4);
    int*    bsum   = (int*)   alloc((size_t)((ncnt + 255) / 256) * 4);
    int*    bb     = (int*)   alloc((size_t)(nbuck + 1) * 4);
    int*    rowptr = (int*)   alloc((size_t)(nN + 1) * 4);
    int*    col    = (int*)   alloc((size_t)E * 4);
    ushort* AbufA  = (ushort*)alloc((size_t)nN * 256 * 2);    // [agg | feat] bf16
    ushort* AbufB  = (ushort*)alloc((size_t)nN * 256 * 2);
    ushort* Wtg0   = (ushort*)alloc((size_t)128 * 256 * 2);
    ushort* Wtg1   = (ushort*)alloc((size_t)128 * 256 * 2);
    ushort* W2tg   = (ushort*)alloc((size_t)80 * 128 * 2);
    // ebuf aliases AbufB: dead after k_bfine, first AbufB write is layer-0 GEMM
    uint*   ebuf   = (uint*)AbufB;
    // P/R alias into AbufA (fully dead after layer-1 gather reads AbufB)
    ushort* Pbuf   = AbufA;                    // [N,40] bf16 packed
    ushort* Rbuf   = AbufA + (size_t)nN * 40;  // [N,40] bf16
    float*  logits = (float*)d_out;

    const int GATH_BLKS = (nN + 7) / 8;        // 8 nodes per block (2 per wave)
    const int G40_BLKS  = (nN + 15) / 16;      // 16 nodes per block (4 per wave)
    const int GEMM_BLKS = (nN + 127) / 128;
    const int n4        = nN * 32;
    const int NBSC      = (ncnt + 255) / 256;

    // ---- CSR build (LDS-atomic bucket sort, parallel scan) + cast + weight prep
    k_bcount<<<NBLK_A, 256, 0, stream>>>(dst, cnt, E, nbuck, x, AbufA, n4,
                                         Wl0, Wr0, Wl1, Wr1, Wl2, Wr2,
                                         Wtg0, Wtg1, W2tg);
    k_scanA <<<NBSC, 256, 0, stream>>>(cnt, bsum, ncnt);
    k_scan2 <<<1, 512, 0, stream>>>(bsum, NBSC, bb, nbuck, E);
    k_bplace<<<NBLK_A, 256, 0, stream>>>(src, dst, cnt, bsum, ebuf, E, nbuck);
    k_bfine <<<nbuck, 1024, 0, stream>>>(ebuf, bb, rowptr, col, nN, nbuck, E);

    // ---- layer 0
    k_gather128<<<GATH_BLKS, 256, 0, stream>>>(AbufA + 128, AbufA, rowptr, col, nN);
    k_gemm_mfma<<<GEMM_BLKS, 256, 0, stream>>>(
        AbufA, 256, Wtg0, b0, AbufB + 128, 256, nN);

    // ---- layer 1 gather, then fused layer-1 GEMM + layer-2 projection
    k_gather128<<<GATH_BLKS, 256, 0, stream>>>(AbufB + 128, AbufB, rowptr, col, nN);
    k_gemm12<<<GEMM_BLKS, 256, 0, stream>>>(
        AbufB, Wtg1, b1, W2tg, b2, Pbuf, Rbuf, nN);

    // ---- 40-dim gather + log_softmax
    k_gather40_lsm<<<G40_BLKS, 256, 0, stream>>>(Pbuf, Rbuf, rowptr, col, logits, nN);
}